// Round 9
// baseline (343.207 us; speedup 1.0000x reference)
//
#include <hip/hip_runtime.h>

#define NN 50000
#define NE 800000
#define NB 256
#define BNODES ((NN + NB - 1) / NB)  // 196 nodes per bucket
static constexpr float BN_EPS = 1e-5f;

typedef __attribute__((ext_vector_type(8))) short bf16x8;
typedef __attribute__((ext_vector_type(4))) float f32x4;

__device__ inline unsigned short f2bf(float f) {
  unsigned int u = __float_as_uint(f);
  return (unsigned short)((u + 0x7FFFu + ((u >> 16) & 1u)) >> 16);
}
__device__ inline float bf2f(unsigned int h) { return __uint_as_float(h << 16); }
__device__ inline float bflo(unsigned int u) { return __uint_as_float(u << 16); }
__device__ inline float bfhi(unsigned int u) { return __uint_as_float(u & 0xffff0000u); }
__device__ inline void gl_lds16(const char* g, char* l) {
  __builtin_amdgcn_global_load_lds((const __attribute__((address_space(1))) void*)g,
                                   (__attribute__((address_space(3))) void*)l, 16, 0, 0);
}

// ================= CSR build: bucketed two-phase =================
__global__ void k_bhisto(const int* __restrict__ dst, int* __restrict__ bsize) {
  __shared__ int cnt[NB];
  int t = threadIdx.x;
  cnt[t] = 0;
  __syncthreads();
  int e0 = blockIdx.x * 8192 + t;
#pragma unroll
  for (int i = 0; i < 32; ++i) {
    int e = e0 + i * 256;
    if (e < NE) atomicAdd(&cnt[dst[e] / BNODES], 1);
  }
  __syncthreads();
  if (cnt[t]) atomicAdd(&bsize[t], cnt[t]);
}

__global__ void k_bscan(const int* __restrict__ bsize, int* __restrict__ bbase,
                        int* __restrict__ bcur, int* __restrict__ row_ptr) {
  __shared__ int ts[NB];
  int t = threadIdx.x;
  int v = bsize[t];
  ts[t] = v;
  __syncthreads();
#pragma unroll
  for (int off = 1; off < NB; off <<= 1) {
    int u = (t >= off) ? ts[t - off] : 0;
    __syncthreads();
    ts[t] += u;
    __syncthreads();
  }
  bbase[t] = ts[t] - v;
  bcur[t] = ts[t] - v;
  if (t == NB - 1) { bbase[NB] = ts[t]; row_ptr[NN] = NE; }
}

__global__ void k_bpart(const int* __restrict__ src, const int* __restrict__ dst,
                        int* __restrict__ bcur, uint2* __restrict__ pairs) {
  __shared__ int cnt[NB], lbase[NB], lcur[NB];
  int t = threadIdx.x;
  cnt[t] = 0;
  __syncthreads();
  int e0 = blockIdx.x * 8192 + t;
#pragma unroll
  for (int i = 0; i < 32; ++i) {
    int e = e0 + i * 256;
    if (e < NE) atomicAdd(&cnt[dst[e] / BNODES], 1);
  }
  __syncthreads();
  lbase[t] = cnt[t] ? atomicAdd(&bcur[t], cnt[t]) : 0;
  lcur[t] = 0;
  __syncthreads();
#pragma unroll
  for (int i = 0; i < 32; ++i) {
    int e = e0 + i * 256;
    if (e < NE) {
      int d = dst[e];
      int b = d / BNODES;
      int p = atomicAdd(&lcur[b], 1);
      pairs[(size_t)lbase[b] + p] = uint2{(unsigned)src[e], (unsigned)d};
    }
  }
}

__global__ void k_bscatter(const uint2* __restrict__ pairs, const int* __restrict__ bbase,
                           int* __restrict__ row_ptr, int* __restrict__ col) {
  __shared__ int dcnt[NB], ts[NB], doff[NB], dcur[NB];
  int t = threadIdx.x;
  int b = blockIdx.x;
  int n0 = b * BNODES;
  int ncnt = min(NN - n0, BNODES);
  int e0 = bbase[b], e1 = bbase[b + 1];
  dcnt[t] = 0;
  __syncthreads();
  for (int e = e0 + t; e < e1; e += 256) atomicAdd(&dcnt[pairs[e].y - n0], 1);
  __syncthreads();
  ts[t] = dcnt[t];
  __syncthreads();
#pragma unroll
  for (int off = 1; off < NB; off <<= 1) {
    int u = (t >= off) ? ts[t - off] : 0;
    __syncthreads();
    ts[t] += u;
    __syncthreads();
  }
  doff[t] = ts[t] - dcnt[t];
  dcur[t] = 0;
  if (t < ncnt) row_ptr[n0 + t] = e0 + doff[t];
  __syncthreads();
  for (int e = e0 + t; e < e1; e += 256) {
    uint2 pr = pairs[e];
    int ld = pr.y - n0;
    int p = atomicAdd(&dcur[ld], 1);
    col[e0 + doff[ld] + p] = (int)pr.x;
  }
}

// ================= fused input prep: x -> xbf (stride 84 uints) + XC1 self/zero =================
__global__ void k_prep_x(const float* __restrict__ x, unsigned int* __restrict__ xbu,
                         unsigned int* __restrict__ X1u) {
  int i = blockIdx.x * 256 + threadIdx.x;
  if (i >= NN * 96) return;
  int r = i / 96, q = i - r * 96;
  if (q < 84) {
    int c0 = 2 * q, c1 = c0 + 1;
    float v0 = (c0 < 166) ? x[(size_t)r * 166 + c0] : 0.f;
    float v1 = (c1 < 166) ? x[(size_t)r * 166 + c1] : 0.f;
    unsigned int u = (unsigned)f2bf(v0) | ((unsigned)f2bf(v1) << 16);
    xbu[(size_t)r * 84 + q] = u;
    X1u[(size_t)r * 192 + 96 + q] = u;
  } else {
    int z = q - 84;  // 0..11
    X1u[(size_t)r * 192 + 84 + z] = 0u;
    X1u[(size_t)r * 192 + 180 + z] = 0u;
  }
}

// ================= fused weight packing =================
__global__ void k_pack_w_all(const float* __restrict__ Wl1, const float* __restrict__ Wr1,
                             const float* __restrict__ Wl2, const float* __restrict__ Wr2,
                             const float* __restrict__ Wle, const float* __restrict__ Wre,
                             unsigned short* __restrict__ w1c, unsigned short* __restrict__ w2s,
                             unsigned short* __restrict__ w3s) {
  int idx = blockIdx.x * 256 + threadIdx.x;
  if (idx < 98304) {  // w1c [256][384]
    int n = idx / 384, k = idx - n * 384;
    float v = 0.f;
    if (k < 166) v = Wl1[(size_t)n * 166 + k];
    else if (k >= 192 && k < 358) v = Wr1[(size_t)n * 166 + (k - 192)];
    w1c[idx] = f2bf(v);
  } else if (idx < 163840) {  // w2s [256][256]
    int j = idx - 98304;
    int n = j / 256, k = j - n * 256;
    w2s[j] = f2bf(n < 128 ? Wl2[(size_t)n * 256 + k] : Wr2[(size_t)(n - 128) * 256 + k]);
  } else if (idx < 180224) {  // w3s [128][128]
    int j = idx - 163840;
    int n = j / 128, k = j - n * 128;
    w3s[j] = f2bf(n < 64 ? Wle[(size_t)n * 128 + k] : Wre[(size_t)(n - 64) * 128 + k]);
  }
}

// ================= uint2-gather mean aggregation =================
// D cols gathered; lane holds uint2 (4 bf16). LPE lanes/edge, EPW edges/wave-iter,
// validity-masked chunks of 8 edges. Wave = one node. 4 nodes/block.
template <int D, bool FUSE, bool OUTBF, bool CLS>
__global__ __launch_bounds__(256) void k_agg2(
    const unsigned int* __restrict__ feat, int fs2,     // uint2 row stride
    const int* __restrict__ row_ptr, const int* __restrict__ col,
    const unsigned int* __restrict__ self, int ss2,     // uint2 row stride of self base
    const float* __restrict__ bias,
    void* __restrict__ outv, int os,                    // uint2 stride (OUTBF) or float4 stride
    const float* __restrict__ Wc, const float* __restrict__ bc,
    float* __restrict__ logits) {
  constexpr int D2 = D / 2;             // uints per row
  constexpr int LPE = (D2 + 1) / 2;     // lanes per edge: 42 / 32 / 16
  constexpr int EPW = 64 / LPE;         // 1 / 2 / 4
  constexpr int CH = 8;                 // edges per chunk
  constexpr int IT = CH / EPW;
  int node = blockIdx.x * 4 + (threadIdx.x >> 6);
  if (node >= NN) return;
  int lane = threadIdx.x & 63;
  int sub = lane / LPE;
  int li = lane % LPE;
  bool lactive = sub < EPW;
  int beg = row_ptr[node], end = row_ptr[node + 1];
  const uint2* f2 = (const uint2*)feat;

  float4 acc = {0.f, 0.f, 0.f, 0.f};
  for (int j = beg; j < end; j += CH) {
    uint2 t[IT];
#pragma unroll
    for (int it = 0; it < IT; ++it) {
      int e = j + it * EPW + sub;
      bool v = lactive && (e < end);
      int c = v ? col[e] : 0;
      t[it] = v ? f2[(size_t)c * fs2 + li] : uint2{0u, 0u};
    }
#pragma unroll
    for (int it = 0; it < IT; ++it) {
      acc.x += bflo(t[it].x); acc.y += bfhi(t[it].x);
      acc.z += bflo(t[it].y); acc.w += bfhi(t[it].y);
    }
  }
  if constexpr (EPW > 1) {
#pragma unroll
    for (int m = LPE; m < 64; m <<= 1) {
      acc.x += __shfl_xor(acc.x, m);
      acc.y += __shfl_xor(acc.y, m);
      acc.z += __shfl_xor(acc.z, m);
      acc.w += __shfl_xor(acc.w, m);
    }
  }
  if (sub == 0) {
    float inv = 1.0f / fmaxf((float)(end - beg), 1.0f);
    acc.x *= inv; acc.y *= inv; acc.z *= inv; acc.w *= inv;
    if constexpr (FUSE) {
      uint2 s = ((const uint2*)self)[(size_t)node * ss2 + li];
      float4 bv = *reinterpret_cast<const float4*>(bias + 4 * li);
      acc.x += bflo(s.x) + bv.x; acc.y += bfhi(s.x) + bv.y;
      acc.z += bflo(s.y) + bv.z; acc.w += bfhi(s.y) + bv.w;
    }
    if constexpr (OUTBF) {
      uint2 o;
      o.x = (unsigned)f2bf(acc.x) | ((unsigned)f2bf(acc.y) << 16);
      o.y = (unsigned)f2bf(acc.z) | ((unsigned)f2bf(acc.w) << 16);
      ((uint2*)outv)[(size_t)node * os + li] = o;
    } else {
      ((float4*)outv)[(size_t)node * os + li] = acc;
    }
    if constexpr (CLS) {
      float s0 = acc.x * Wc[4 * li] + acc.y * Wc[4 * li + 1] + acc.z * Wc[4 * li + 2] + acc.w * Wc[4 * li + 3];
      float s1 = acc.x * Wc[64 + 4 * li] + acc.y * Wc[64 + 4 * li + 1] + acc.z * Wc[64 + 4 * li + 2] + acc.w * Wc[64 + 4 * li + 3];
#pragma unroll
      for (int m = 1; m < 16; m <<= 1) {
        s0 += __shfl_xor(s0, m);
        s1 += __shfl_xor(s1, m);
      }
      if (li == 0) {
        logits[node * 2 + 0] = s0 + bc[0];
        logits[node * 2 + 1] = s1 + bc[1];
      }
    }
  }
}

// ================= bf16 MFMA GEMM, 2-phase pipelined global_load_lds =================
template <bool BIASED, bool STATS>
__global__ __launch_bounds__(256) void k_gemm_mfma(
    const unsigned short* __restrict__ A, int KC,
    const unsigned short* __restrict__ W,
    const float* __restrict__ bias,
    unsigned short* __restrict__ out, int Ntot,
    float* __restrict__ statacc) {
  __shared__ __align__(16) char lds[65536];
  int tid = threadIdx.x;
  int lane = tid & 63;
  int w = tid >> 6;
  int wr = w >> 1, wc = w & 1;
  int m0 = blockIdx.x * 128;
  int n0 = blockIdx.y * 128;

  int srow = lane >> 3;
  int scol = (lane & 7) << 4;
  int ssw = scol ^ (srow << 4);
  const char* Ab = (const char*)A;
  const char* Wb = (const char*)W;

  f32x4 acc[4][4];
#pragma unroll
  for (int i = 0; i < 4; ++i)
#pragma unroll
    for (int j = 0; j < 4; ++j) acc[i][j] = f32x4{0.f, 0.f, 0.f, 0.f};

  auto stage = [&](int buf, int k0) {
    char* dst = lds + buf * 32768 + w * 4096;
#pragma unroll
    for (int i = 0; i < 4; ++i) {
      int row = w * 32 + i * 8 + srow;
      int ga = m0 + row;
      ga = ga < NN ? ga : NN - 1;
      gl_lds16(Ab + ((size_t)ga * KC + k0) * 2 + ssw, dst + i * 1024);
      gl_lds16(Wb + ((size_t)(n0 + row) * KC + k0) * 2 + ssw, dst + 16384 + i * 1024);
    }
  };
  auto compute = [&](int buf) {
    char* lA = lds + buf * 32768;
    char* lB = lA + 16384;
#pragma unroll
    for (int ks = 0; ks < 2; ++ks) {
      bf16x8 af[4], bfr[4];
      int ac = ks * 64 + ((lane >> 4) << 4);
#pragma unroll
      for (int f = 0; f < 4; ++f) {
        int ar = wr * 64 + f * 16 + (lane & 15);
        af[f] = *reinterpret_cast<const bf16x8*>(lA + ar * 128 + (ac ^ ((ar & 7) << 4)));
        int br = wc * 64 + f * 16 + (lane & 15);
        bfr[f] = *reinterpret_cast<const bf16x8*>(lB + br * 128 + (ac ^ ((br & 7) << 4)));
      }
#pragma unroll
      for (int fm = 0; fm < 4; ++fm)
#pragma unroll
        for (int fn = 0; fn < 4; ++fn)
          acc[fm][fn] = __builtin_amdgcn_mfma_f32_16x16x32_bf16(af[fm], bfr[fn], acc[fm][fn], 0, 0, 0);
    }
  };

  int nt = KC >> 6;
  stage(0, 0);
  __syncthreads();
  int cur = 0;
  for (int t = 0; t < nt; ++t) {
    if (t + 1 < nt) stage(cur ^ 1, (t + 1) << 6);
    compute(cur);
    __syncthreads();
    cur ^= 1;
  }

  int nbase = n0 + wc * 64 + (lane & 15);
  float bv[4] = {0.f, 0.f, 0.f, 0.f};
  if constexpr (BIASED) {
#pragma unroll
    for (int fn = 0; fn < 4; ++fn) bv[fn] = bias[nbase + fn * 16];
  }
  float ssum[4] = {0.f, 0.f, 0.f, 0.f}, sqs[4] = {0.f, 0.f, 0.f, 0.f};
#pragma unroll
  for (int fm = 0; fm < 4; ++fm) {
    int mbase = m0 + wr * 64 + fm * 16 + ((lane >> 4) << 2);
#pragma unroll
    for (int j = 0; j < 4; ++j) {
      int m = mbase + j;
      if (m < NN) {
#pragma unroll
        for (int fn = 0; fn < 4; ++fn) {
          float v = acc[fm][fn][j] + bv[fn];
          out[(size_t)m * Ntot + nbase + fn * 16] = f2bf(v);
          if constexpr (STATS) { ssum[fn] += v; sqs[fn] += v * v; }
        }
      }
    }
  }
  if constexpr (STATS) {
#pragma unroll
    for (int fn = 0; fn < 4; ++fn) {
      float s = ssum[fn], q = sqs[fn];
      s += __shfl_xor(s, 16); s += __shfl_xor(s, 32);
      q += __shfl_xor(q, 16); q += __shfl_xor(q, 32);
      if (lane < 16) {
        atomicAdd(&statacc[nbase + fn * 16], s);
        atomicAdd(&statacc[Ntot + nbase + fn * 16], q);
      }
    }
  }
}

// ================= BatchNorm =================
template <int N, bool BF>
__global__ __launch_bounds__(256) void k_bn_stats2(const void* __restrict__ hv,
                                                   float* __restrict__ acc) {
  constexpr int CP = N / 2;
  constexpr int RG = 256 / CP;
  int cp = threadIdx.x % CP, rg = threadIdx.x / CP;
  int rpb = (NN + gridDim.x - 1) / gridDim.x;
  int r0 = blockIdx.x * rpb, r1 = min(r0 + rpb, NN);
  float s0 = 0.f, s1 = 0.f, q0 = 0.f, q1 = 0.f;
  for (int r = r0 + rg; r < r1; r += RG) {
    float v0, v1;
    if constexpr (BF) {
      unsigned int u = ((const unsigned int*)hv)[(size_t)r * CP + cp];
      v0 = bf2f(u & 0xffffu); v1 = bf2f(u >> 16);
    } else {
      float2 u = ((const float2*)hv)[(size_t)r * CP + cp];
      v0 = u.x; v1 = u.y;
    }
    s0 += v0; s1 += v1; q0 += v0 * v0; q1 += v1 * v1;
  }
  __shared__ float l0[256], l1[256], l2[256], l3[256];
  l0[threadIdx.x] = s0; l1[threadIdx.x] = s1; l2[threadIdx.x] = q0; l3[threadIdx.x] = q1;
  __syncthreads();
  if (rg == 0) {
#pragma unroll
    for (int g = 1; g < RG; ++g) {
      s0 += l0[g * CP + cp]; s1 += l1[g * CP + cp];
      q0 += l2[g * CP + cp]; q1 += l3[g * CP + cp];
    }
    atomicAdd(&acc[2 * cp], s0);
    atomicAdd(&acc[2 * cp + 1], s1);
    atomicAdd(&acc[N + 2 * cp], q0);
    atomicAdd(&acc[N + 2 * cp + 1], q1);
  }
}

template <int N, bool INF32>
__global__ void k_bn_apply2(const void* __restrict__ hv, const float* __restrict__ acc,
                            const float* __restrict__ g, const float* __restrict__ b,
                            unsigned int* __restrict__ out) {
  constexpr int N2 = N / 2;
  int p = blockIdx.x * 256 + threadIdx.x;
  if (p >= NN * N2) return;
  int cp = p % N2;
  int c0 = 2 * cp, c1 = c0 + 1;
  float v0, v1;
  if constexpr (INF32) {
    float2 u = reinterpret_cast<const float2*>(hv)[p];
    v0 = u.x; v1 = u.y;
  } else {
    unsigned int u = reinterpret_cast<const unsigned int*>(hv)[p];
    v0 = bf2f(u & 0xffffu); v1 = bf2f(u >> 16);
  }
  float m0 = acc[c0] * (1.0f / NN);
  float m1 = acc[c1] * (1.0f / NN);
  float sc0 = g[c0] * rsqrtf(acc[N + c0] * (1.0f / NN) - m0 * m0 + BN_EPS);
  float sc1 = g[c1] * rsqrtf(acc[N + c1] * (1.0f / NN) - m1 * m1 + BN_EPS);
  float r0 = fmaxf((v0 - m0) * sc0 + b[c0], 0.f);
  float r1 = fmaxf((v1 - m1) * sc1 + b[c1], 0.f);
  out[p] = (unsigned int)f2bf(r0) | ((unsigned int)f2bf(r1) << 16);
}

extern "C" void kernel_launch(void* const* d_in, const int* in_sizes, int n_in,
                              void* d_out, int out_size, void* d_ws, size_t ws_size,
                              hipStream_t stream) {
  const float* x   = (const float*)d_in[0];
  const int* ei    = (const int*)d_in[1];
  const float* Wl1 = (const float*)d_in[2];
  const float* Wr1 = (const float*)d_in[3];
  const float* b1  = (const float*)d_in[4];
  const float* Wl2 = (const float*)d_in[5];
  const float* Wr2 = (const float*)d_in[6];
  const float* b2  = (const float*)d_in[7];
  const float* Wle = (const float*)d_in[8];
  const float* Wre = (const float*)d_in[9];
  const float* be  = (const float*)d_in[10];
  const float* g1  = (const float*)d_in[11];
  const float* bt1 = (const float*)d_in[12];
  const float* g2  = (const float*)d_in[13];
  const float* bt2 = (const float*)d_in[14];
  const float* Wc  = (const float*)d_in[15];
  const float* bc  = (const float*)d_in[16];

  const int* src = ei;
  const int* dst = ei + NE;

  char* ws = (char*)d_ws;
  size_t off = 0;
  auto take = [&](size_t bytes) -> char* {
    char* p = ws + off;
    off = (off + bytes + 255) & ~(size_t)255;
    return p;
  };
  int* row_ptr   = (int*)take((size_t)(NN + 1) * 4);
  int* bkt_size  = (int*)take(1024);      // |
  float* bnacc1  = (float*)take(2048);    // | one contiguous memset region (5120 B)
  float* bnacc2  = (float*)take(2048);    // |
  int* bkt_base  = (int*)take((NB + 1) * 4);
  int* bkt_cur   = (int*)take(NB * 4);
  uint2* pairs   = (uint2*)take((size_t)NE * 8);
  int* col       = (int*)take((size_t)NE * 4);
  unsigned short* w1c = (unsigned short*)take((size_t)256 * 384 * 2);
  unsigned short* w2s = (unsigned short*)take((size_t)256 * 256 * 2);
  unsigned short* w3s = (unsigned short*)take((size_t)128 * 128 * 2);
  unsigned int* xbu = (unsigned int*)take((size_t)NN * 84 * 4);  // bf16 x, stride 84 uints
  char* P0 = take((size_t)NN * 384 * 2);
  char* P1 = take((size_t)NN * 256 * 2);

  unsigned short* XC1   = (unsigned short*)P0;  // [NN][384]
  unsigned short* h1raw = (unsigned short*)P1;  // [NN][256]
  unsigned short* h1    = (unsigned short*)P0;  // [NN][256]
  unsigned short* z2    = (unsigned short*)P1;  // [NN][256]
  float*          h2raw = (float*)P0;           // [NN][128]
  unsigned short* h2    = (unsigned short*)P1;  // [NN][128]
  unsigned short* z3    = (unsigned short*)P0;  // [NN][128]

  float* logits = (float*)d_out;
  float* emb    = (float*)d_out + (size_t)NN * 2;

  // one memset: bkt_size + bnacc1 + bnacc2 (contiguous)
  hipMemsetAsync(bkt_size, 0, 5120, stream);

  // CSR build
  k_bhisto<<<(NE + 8191) / 8192, 256, 0, stream>>>(dst, bkt_size);
  k_bscan<<<1, NB, 0, stream>>>(bkt_size, bkt_base, bkt_cur, row_ptr);
  k_bpart<<<(NE + 8191) / 8192, 256, 0, stream>>>(src, dst, bkt_cur, pairs);
  k_bscatter<<<NB, NB, 0, stream>>>(pairs, bkt_base, row_ptr, col);

  // input prep + weight packing (fused)
  k_prep_x<<<(NN * 96 + 255) / 256, 256, 0, stream>>>(x, xbu, (unsigned int*)XC1);
  k_pack_w_all<<<(180224 + 255) / 256, 256, 0, stream>>>(Wl1, Wr1, Wl2, Wr2, Wle, Wre, w1c, w2s, w3s);

  // ---- layer 1: XC1 = [agg(x) | x] @ w1c + b1 -> h1raw (+fused BN stats); BN+ReLU -> h1 ----
  k_agg2<166, false, true, false><<<(NN + 3) / 4, 256, 0, stream>>>(
      xbu, 42, row_ptr, col, nullptr, 0, nullptr, (unsigned int*)XC1, 96, nullptr, nullptr, nullptr);
  {
    dim3 g((NN + 127) / 128, 2);
    k_gemm_mfma<true, true><<<g, 256, 0, stream>>>(XC1, 384, w1c, b1, h1raw, 256, bnacc1);
  }
  k_bn_apply2<256, false><<<(NN * 128 + 255) / 256, 256, 0, stream>>>(
      h1raw, bnacc1, g1, bt1, (unsigned int*)h1);

  // ---- layer 2: z2 = h1 @ [Wl2;Wr2]^T; h2raw = agg(z2[:,:128]) + z2[:,128:] + b2 ----
  {
    dim3 g((NN + 127) / 128, 2);
    k_gemm_mfma<false, false><<<g, 256, 0, stream>>>(h1, 256, w2s, nullptr, z2, 256, nullptr);
  }
  k_agg2<128, true, false, false><<<(NN + 3) / 4, 256, 0, stream>>>(
      (const unsigned int*)z2, 64, row_ptr, col, (const unsigned int*)z2 + 64, 64, b2,
      h2raw, 32, nullptr, nullptr, nullptr);
  k_bn_stats2<128, false><<<512, 256, 0, stream>>>(h2raw, bnacc2);
  k_bn_apply2<128, true><<<(NN * 64 + 255) / 256, 256, 0, stream>>>(
      h2raw, bnacc2, g2, bt2, (unsigned int*)h2);

  // ---- layer 3: z3 = h2 @ [Wle;Wre]^T; emb = agg(z3[:,:64]) + z3[:,64:] + be; fused classifier ----
  {
    dim3 g((NN + 127) / 128, 1);
    k_gemm_mfma<false, false><<<g, 256, 0, stream>>>(h2, 128, w3s, nullptr, z3, 128, nullptr);
  }
  k_agg2<64, true, false, true><<<(NN + 3) / 4, 256, 0, stream>>>(
      (const unsigned int*)z3, 32, row_ptr, col, (const unsigned int*)z3 + 32, 32, be,
      emb, 16, Wc, bc, logits);
}

// Round 10
// 309.418 us; speedup vs baseline: 1.1092x; 1.1092x over previous
//
#include <hip/hip_runtime.h>

#define NN 50000
#define NE 800000
#define NB 256
#define BNODES ((NN + NB - 1) / NB)  // 196 nodes per bucket
#define CAP 4096                     // bucket window capacity (mean 3125, +17 sigma)
static constexpr float BN_EPS = 1e-5f;

typedef __attribute__((ext_vector_type(8))) short bf16x8;
typedef __attribute__((ext_vector_type(4))) float f32x4;

__device__ inline unsigned short f2bf(float f) {
  unsigned int u = __float_as_uint(f);
  return (unsigned short)((u + 0x7FFFu + ((u >> 16) & 1u)) >> 16);
}
__device__ inline float bf2f(unsigned int h) { return __uint_as_float(h << 16); }
__device__ inline void gl_lds16(const char* g, char* l) {
  __builtin_amdgcn_global_load_lds((const __attribute__((address_space(1))) void*)g,
                                   (__attribute__((address_space(3))) void*)l, 16, 0, 0);
}

// ================= CSR build: fixed-window bucketed scatter =================
// A: partition edges into bucket windows (pairs[b*CAP ...]), atomic window cursors
__global__ void k_bpart(const int* __restrict__ src, const int* __restrict__ dst,
                        int* __restrict__ bcur, uint2* __restrict__ pairs) {
  __shared__ int cnt[NB], lbase[NB], lcur[NB];
  int t = threadIdx.x;
  cnt[t] = 0;
  __syncthreads();
  int e0 = blockIdx.x * 8192 + t;
#pragma unroll
  for (int i = 0; i < 32; ++i) {
    int e = e0 + i * 256;
    if (e < NE) atomicAdd(&cnt[dst[e] / BNODES], 1);
  }
  __syncthreads();
  lbase[t] = cnt[t] ? (t * CAP + atomicAdd(&bcur[t], cnt[t])) : 0;
  lcur[t] = 0;
  __syncthreads();
#pragma unroll
  for (int i = 0; i < 32; ++i) {
    int e = e0 + i * 256;
    if (e < NE) {
      int d = dst[e];
      int b = d / BNODES;
      int p = atomicAdd(&lcur[b], 1);
      pairs[(size_t)lbase[b] + p] = uint2{(unsigned)src[e], (unsigned)d};
    }
  }
}

// B: per-bucket: degree count -> local scan -> begend + col scatter (window-local)
__global__ void k_bscatter(const uint2* __restrict__ pairs, const int* __restrict__ bcur,
                           int2* __restrict__ begend, int* __restrict__ col) {
  __shared__ int dcnt[NB], ts[NB], doff[NB], dcur[NB];
  int t = threadIdx.x;
  int b = blockIdx.x;
  int n0 = b * BNODES;
  int ncnt = min(NN - n0, BNODES);
  int e0 = b * CAP, e1 = e0 + bcur[b];
  dcnt[t] = 0;
  __syncthreads();
  for (int e = e0 + t; e < e1; e += 256) atomicAdd(&dcnt[pairs[e].y - n0], 1);
  __syncthreads();
  ts[t] = dcnt[t];
  __syncthreads();
#pragma unroll
  for (int off = 1; off < NB; off <<= 1) {
    int u = (t >= off) ? ts[t - off] : 0;
    __syncthreads();
    ts[t] += u;
    __syncthreads();
  }
  doff[t] = ts[t] - dcnt[t];
  dcur[t] = 0;
  if (t < ncnt) begend[n0 + t] = int2{e0 + doff[t], e0 + doff[t] + dcnt[t]};
  __syncthreads();
  for (int e = e0 + t; e < e1; e += 256) {
    uint2 pr = pairs[e];
    int ld = pr.y - n0;
    int p = atomicAdd(&dcur[ld], 1);
    col[e0 + doff[ld] + p] = (int)pr.x;
  }
}

// ================= fused input prep: x -> xbu (stride 96 uints, line-aligned) + XC1 =====
__global__ void k_prep_x(const float* __restrict__ x, unsigned int* __restrict__ xbu,
                         unsigned int* __restrict__ X1u) {
  int i = blockIdx.x * 256 + threadIdx.x;
  if (i >= NN * 96) return;
  int r = i / 96, q = i - r * 96;
  if (q < 84) {
    int c0 = 2 * q, c1 = c0 + 1;
    float v0 = (c0 < 166) ? x[(size_t)r * 166 + c0] : 0.f;
    float v1 = (c1 < 166) ? x[(size_t)r * 166 + c1] : 0.f;
    unsigned int u = (unsigned)f2bf(v0) | ((unsigned)f2bf(v1) << 16);
    xbu[(size_t)r * 96 + q] = u;
    X1u[(size_t)r * 192 + 96 + q] = u;
  } else {
    int z = q - 84;  // 0..11
    X1u[(size_t)r * 192 + 84 + z] = 0u;
    X1u[(size_t)r * 192 + 180 + z] = 0u;
    if (z == 0) X1u[(size_t)r * 192 + 83] = 0u;  // cols 166,167 (agg writes only uints 0..82)
  }
}

// ================= fused weight packing =================
__global__ void k_pack_w_all(const float* __restrict__ Wl1, const float* __restrict__ Wr1,
                             const float* __restrict__ Wl2, const float* __restrict__ Wr2,
                             const float* __restrict__ Wle, const float* __restrict__ Wre,
                             unsigned short* __restrict__ w1c, unsigned short* __restrict__ w2s,
                             unsigned short* __restrict__ w3s) {
  int idx = blockIdx.x * 256 + threadIdx.x;
  if (idx < 98304) {  // w1c [256][384]
    int n = idx / 384, k = idx - n * 384;
    float v = 0.f;
    if (k < 166) v = Wl1[(size_t)n * 166 + k];
    else if (k >= 192 && k < 358) v = Wr1[(size_t)n * 166 + (k - 192)];
    w1c[idx] = f2bf(v);
  } else if (idx < 163840) {  // w2s [256][256]
    int j = idx - 98304;
    int n = j / 256, k = j - n * 256;
    w2s[j] = f2bf(n < 128 ? Wl2[(size_t)n * 256 + k] : Wr2[(size_t)(n - 128) * 256 + k]);
  } else if (idx < 180224) {  // w3s [128][128]
    int j = idx - 163840;
    int n = j / 128, k = j - n * 128;
    w3s[j] = f2bf(n < 64 ? Wle[(size_t)n * 128 + k] : Wre[(size_t)(n - 64) * 128 + k]);
  }
}

// ================= bf16 mean aggregation (round-8 proven structure, begend CSR) =========
// lane = uint (2 cols); U-edge pointer-batch unroll; optional fused self+bias / classifier
template <int D, int U, bool FUSE, bool OUTBF, bool CLS>
__global__ __launch_bounds__(256) void k_aggb(
    const unsigned int* __restrict__ feat, int fsu,
    const int2* __restrict__ begend, const int* __restrict__ col,
    const unsigned int* __restrict__ self, int ssu,
    const float* __restrict__ bias,
    void* __restrict__ outv, int osu,
    const float* __restrict__ Wc, const float* __restrict__ bc,
    float* __restrict__ logits) {
  constexpr int D2 = D / 2;
  constexpr int LPN = (D2 < 64) ? D2 : 64;
  constexpr int NPB = 256 / LPN;
  constexpr int C = (D2 + LPN - 1) / LPN;
  int node = blockIdx.x * NPB + threadIdx.x / LPN;
  if (node >= NN) return;
  int lane = threadIdx.x % LPN;
  int2 be = begend[node];
  int beg = be.x, end = be.y;
  float ax[C], ay[C];
#pragma unroll
  for (int c = 0; c < C; ++c) { ax[c] = 0.f; ay[c] = 0.f; }

  int j = beg;
  for (; j + U <= end; j += U) {
    const unsigned int* fp[U];
#pragma unroll
    for (int u = 0; u < U; ++u) fp[u] = feat + (size_t)col[j + u] * fsu;
#pragma unroll
    for (int c = 0; c < C; ++c) {
      int p = lane + c * LPN;
      unsigned int t[U];
#pragma unroll
      for (int u = 0; u < U; ++u) t[u] = (p < D2) ? fp[u][p] : 0u;
#pragma unroll
      for (int u = 0; u < U; ++u) {
        ax[c] += bf2f(t[u] & 0xffffu);
        ay[c] += bf2f(t[u] >> 16);
      }
    }
  }
  for (; j < end; ++j) {
    const unsigned int* fr = feat + (size_t)col[j] * fsu;
#pragma unroll
    for (int c = 0; c < C; ++c) {
      int p = lane + c * LPN;
      if (p < D2) {
        unsigned int t = fr[p];
        ax[c] += bf2f(t & 0xffffu);
        ay[c] += bf2f(t >> 16);
      }
    }
  }
  float inv = 1.0f / fmaxf((float)(end - beg), 1.0f);
  float s0 = 0.f, s1 = 0.f;
#pragma unroll
  for (int c = 0; c < C; ++c) {
    int p = lane + c * LPN;
    if (p < D2) {
      float vx = ax[c] * inv, vy = ay[c] * inv;
      if constexpr (FUSE) {
        unsigned int s = self[(size_t)node * ssu + p];
        vx += bf2f(s & 0xffffu) + bias[2 * p];
        vy += bf2f(s >> 16) + bias[2 * p + 1];
      }
      if constexpr (OUTBF) {
        unsigned int o = (unsigned int)f2bf(vx) | ((unsigned int)f2bf(vy) << 16);
        ((unsigned int*)outv)[(size_t)node * osu + p] = o;
      } else {
        float2 o{vx, vy};
        *reinterpret_cast<float2*>((float*)outv + (size_t)node * osu + 2 * p) = o;
      }
      if constexpr (CLS) {
        s0 += vx * Wc[2 * p] + vy * Wc[2 * p + 1];
        s1 += vx * Wc[64 + 2 * p] + vy * Wc[64 + 2 * p + 1];
      }
    }
  }
  if constexpr (CLS) {
#pragma unroll
    for (int m = 1; m < LPN; m <<= 1) {
      s0 += __shfl_xor(s0, m);
      s1 += __shfl_xor(s1, m);
    }
    if (lane == 0) {
      logits[node * 2 + 0] = s0 + bc[0];
      logits[node * 2 + 1] = s1 + bc[1];
    }
  }
}

// ================= bf16 MFMA GEMM, 2-phase pipelined global_load_lds =================
template <bool BIASED, bool STATS>
__global__ __launch_bounds__(256) void k_gemm_mfma(
    const unsigned short* __restrict__ A, int KC,
    const unsigned short* __restrict__ W,
    const float* __restrict__ bias,
    unsigned short* __restrict__ out, int Ntot,
    float* __restrict__ statacc) {
  __shared__ __align__(16) char lds[65536];
  int tid = threadIdx.x;
  int lane = tid & 63;
  int w = tid >> 6;
  int wr = w >> 1, wc = w & 1;
  int m0 = blockIdx.x * 128;
  int n0 = blockIdx.y * 128;

  int srow = lane >> 3;
  int scol = (lane & 7) << 4;
  int ssw = scol ^ (srow << 4);
  const char* Ab = (const char*)A;
  const char* Wb = (const char*)W;

  f32x4 acc[4][4];
#pragma unroll
  for (int i = 0; i < 4; ++i)
#pragma unroll
    for (int j = 0; j < 4; ++j) acc[i][j] = f32x4{0.f, 0.f, 0.f, 0.f};

  auto stage = [&](int buf, int k0) {
    char* dst = lds + buf * 32768 + w * 4096;
#pragma unroll
    for (int i = 0; i < 4; ++i) {
      int row = w * 32 + i * 8 + srow;
      int ga = m0 + row;
      ga = ga < NN ? ga : NN - 1;
      gl_lds16(Ab + ((size_t)ga * KC + k0) * 2 + ssw, dst + i * 1024);
      gl_lds16(Wb + ((size_t)(n0 + row) * KC + k0) * 2 + ssw, dst + 16384 + i * 1024);
    }
  };
  auto compute = [&](int buf) {
    char* lA = lds + buf * 32768;
    char* lB = lA + 16384;
#pragma unroll
    for (int ks = 0; ks < 2; ++ks) {
      bf16x8 af[4], bfr[4];
      int ac = ks * 64 + ((lane >> 4) << 4);
#pragma unroll
      for (int f = 0; f < 4; ++f) {
        int ar = wr * 64 + f * 16 + (lane & 15);
        af[f] = *reinterpret_cast<const bf16x8*>(lA + ar * 128 + (ac ^ ((ar & 7) << 4)));
        int br = wc * 64 + f * 16 + (lane & 15);
        bfr[f] = *reinterpret_cast<const bf16x8*>(lB + br * 128 + (ac ^ ((br & 7) << 4)));
      }
#pragma unroll
      for (int fm = 0; fm < 4; ++fm)
#pragma unroll
        for (int fn = 0; fn < 4; ++fn)
          acc[fm][fn] = __builtin_amdgcn_mfma_f32_16x16x32_bf16(af[fm], bfr[fn], acc[fm][fn], 0, 0, 0);
    }
  };

  int nt = KC >> 6;
  stage(0, 0);
  __syncthreads();
  int cur = 0;
  for (int t = 0; t < nt; ++t) {
    if (t + 1 < nt) stage(cur ^ 1, (t + 1) << 6);
    compute(cur);
    __syncthreads();
    cur ^= 1;
  }

  int nbase = n0 + wc * 64 + (lane & 15);
  float bv[4] = {0.f, 0.f, 0.f, 0.f};
  if constexpr (BIASED) {
#pragma unroll
    for (int fn = 0; fn < 4; ++fn) bv[fn] = bias[nbase + fn * 16];
  }
  float ssum[4] = {0.f, 0.f, 0.f, 0.f}, sqs[4] = {0.f, 0.f, 0.f, 0.f};
#pragma unroll
  for (int fm = 0; fm < 4; ++fm) {
    int mbase = m0 + wr * 64 + fm * 16 + ((lane >> 4) << 2);
#pragma unroll
    for (int j = 0; j < 4; ++j) {
      int m = mbase + j;
      if (m < NN) {
#pragma unroll
        for (int fn = 0; fn < 4; ++fn) {
          float v = acc[fm][fn][j] + bv[fn];
          out[(size_t)m * Ntot + nbase + fn * 16] = f2bf(v);
          if constexpr (STATS) { ssum[fn] += v; sqs[fn] += v * v; }
        }
      }
    }
  }
  if constexpr (STATS) {
#pragma unroll
    for (int fn = 0; fn < 4; ++fn) {
      float s = ssum[fn], q = sqs[fn];
      s += __shfl_xor(s, 16); s += __shfl_xor(s, 32);
      q += __shfl_xor(q, 16); q += __shfl_xor(q, 32);
      if (lane < 16) {
        atomicAdd(&statacc[nbase + fn * 16], s);
        atomicAdd(&statacc[Ntot + nbase + fn * 16], q);
      }
    }
  }
}

// ================= BatchNorm =================
template <int N, bool BF>
__global__ __launch_bounds__(256) void k_bn_stats2(const void* __restrict__ hv,
                                                   float* __restrict__ acc) {
  constexpr int CP = N / 2;
  constexpr int RG = 256 / CP;
  int cp = threadIdx.x % CP, rg = threadIdx.x / CP;
  int rpb = (NN + gridDim.x - 1) / gridDim.x;
  int r0 = blockIdx.x * rpb, r1 = min(r0 + rpb, NN);
  float s0 = 0.f, s1 = 0.f, q0 = 0.f, q1 = 0.f;
  for (int r = r0 + rg; r < r1; r += RG) {
    float v0, v1;
    if constexpr (BF) {
      unsigned int u = ((const unsigned int*)hv)[(size_t)r * CP + cp];
      v0 = bf2f(u & 0xffffu); v1 = bf2f(u >> 16);
    } else {
      float2 u = ((const float2*)hv)[(size_t)r * CP + cp];
      v0 = u.x; v1 = u.y;
    }
    s0 += v0; s1 += v1; q0 += v0 * v0; q1 += v1 * v1;
  }
  __shared__ float l0[256], l1[256], l2[256], l3[256];
  l0[threadIdx.x] = s0; l1[threadIdx.x] = s1; l2[threadIdx.x] = q0; l3[threadIdx.x] = q1;
  __syncthreads();
  if (rg == 0) {
#pragma unroll
    for (int g = 1; g < RG; ++g) {
      s0 += l0[g * CP + cp]; s1 += l1[g * CP + cp];
      q0 += l2[g * CP + cp]; q1 += l3[g * CP + cp];
    }
    atomicAdd(&acc[2 * cp], s0);
    atomicAdd(&acc[2 * cp + 1], s1);
    atomicAdd(&acc[N + 2 * cp], q0);
    atomicAdd(&acc[N + 2 * cp + 1], q1);
  }
}

template <int N, bool INF32>
__global__ void k_bn_apply2(const void* __restrict__ hv, const float* __restrict__ acc,
                            const float* __restrict__ g, const float* __restrict__ b,
                            unsigned int* __restrict__ out) {
  constexpr int N2 = N / 2;
  int p = blockIdx.x * 256 + threadIdx.x;
  if (p >= NN * N2) return;
  int cp = p % N2;
  int c0 = 2 * cp, c1 = c0 + 1;
  float v0, v1;
  if constexpr (INF32) {
    float2 u = reinterpret_cast<const float2*>(hv)[p];
    v0 = u.x; v1 = u.y;
  } else {
    unsigned int u = reinterpret_cast<const unsigned int*>(hv)[p];
    v0 = bf2f(u & 0xffffu); v1 = bf2f(u >> 16);
  }
  float m0 = acc[c0] * (1.0f / NN);
  float m1 = acc[c1] * (1.0f / NN);
  float sc0 = g[c0] * rsqrtf(acc[N + c0] * (1.0f / NN) - m0 * m0 + BN_EPS);
  float sc1 = g[c1] * rsqrtf(acc[N + c1] * (1.0f / NN) - m1 * m1 + BN_EPS);
  float r0 = fmaxf((v0 - m0) * sc0 + b[c0], 0.f);
  float r1 = fmaxf((v1 - m1) * sc1 + b[c1], 0.f);
  out[p] = (unsigned int)f2bf(r0) | ((unsigned int)f2bf(r1) << 16);
}

extern "C" void kernel_launch(void* const* d_in, const int* in_sizes, int n_in,
                              void* d_out, int out_size, void* d_ws, size_t ws_size,
                              hipStream_t stream) {
  const float* x   = (const float*)d_in[0];
  const int* ei    = (const int*)d_in[1];
  const float* Wl1 = (const float*)d_in[2];
  const float* Wr1 = (const float*)d_in[3];
  const float* b1  = (const float*)d_in[4];
  const float* Wl2 = (const float*)d_in[5];
  const float* Wr2 = (const float*)d_in[6];
  const float* b2  = (const float*)d_in[7];
  const float* Wle = (const float*)d_in[8];
  const float* Wre = (const float*)d_in[9];
  const float* be  = (const float*)d_in[10];
  const float* g1  = (const float*)d_in[11];
  const float* bt1 = (const float*)d_in[12];
  const float* g2  = (const float*)d_in[13];
  const float* bt2 = (const float*)d_in[14];
  const float* Wc  = (const float*)d_in[15];
  const float* bc  = (const float*)d_in[16];

  const int* src = ei;
  const int* dst = ei + NE;

  char* ws = (char*)d_ws;
  size_t off = 0;
  auto take = [&](size_t bytes) -> char* {
    char* p = ws + off;
    off = (off + bytes + 255) & ~(size_t)255;
    return p;
  };
  int* bkt_cur   = (int*)take(1024);      // |
  float* bnacc1  = (float*)take(2048);    // | one contiguous memset region (5120 B)
  float* bnacc2  = (float*)take(2048);    // |
  int2* begend   = (int2*)take((size_t)NN * 8);
  uint2* pairs   = (uint2*)take((size_t)NB * CAP * 8);
  int* col       = (int*)take((size_t)NB * CAP * 4);
  unsigned short* w1c = (unsigned short*)take((size_t)256 * 384 * 2);
  unsigned short* w2s = (unsigned short*)take((size_t)256 * 256 * 2);
  unsigned short* w3s = (unsigned short*)take((size_t)128 * 128 * 2);
  unsigned int* xbu = (unsigned int*)take((size_t)NN * 96 * 4);  // bf16 x, stride 96 uints
  char* P0 = take((size_t)NN * 384 * 2);
  char* P1 = take((size_t)NN * 256 * 2);

  unsigned short* XC1   = (unsigned short*)P0;  // [NN][384]
  unsigned short* h1raw = (unsigned short*)P1;  // [NN][256]
  unsigned short* h1    = (unsigned short*)P0;  // [NN][256]
  unsigned short* z2    = (unsigned short*)P1;  // [NN][256]
  float*          h2raw = (float*)P0;           // [NN][128]
  unsigned short* h2    = (unsigned short*)P1;  // [NN][128]
  unsigned short* z3    = (unsigned short*)P0;  // [NN][128]

  float* logits = (float*)d_out;
  float* emb    = (float*)d_out + (size_t)NN * 2;

  // one memset: bkt_cur + bnacc1 + bnacc2 (contiguous)
  hipMemsetAsync(bkt_cur, 0, 5120, stream);

  // CSR build (fixed-window, 2 kernels)
  k_bpart<<<(NE + 8191) / 8192, 256, 0, stream>>>(src, dst, bkt_cur, pairs);
  k_bscatter<<<NB, NB, 0, stream>>>(pairs, bkt_cur, begend, col);

  // input prep + weight packing (fused)
  k_prep_x<<<(NN * 96 + 255) / 256, 256, 0, stream>>>(x, xbu, (unsigned int*)XC1);
  k_pack_w_all<<<(180224 + 255) / 256, 256, 0, stream>>>(Wl1, Wr1, Wl2, Wr2, Wle, Wre, w1c, w2s, w3s);

  // ---- layer 1: XC1 = [agg(x) | x] @ w1c + b1 -> h1raw (+fused BN stats); BN+ReLU -> h1 ----
  k_aggb<166, 4, false, true, false><<<(NN + 3) / 4, 256, 0, stream>>>(
      xbu, 96, begend, col, nullptr, 0, nullptr, (unsigned int*)XC1, 192,
      nullptr, nullptr, nullptr);
  {
    dim3 g((NN + 127) / 128, 2);
    k_gemm_mfma<true, true><<<g, 256, 0, stream>>>(XC1, 384, w1c, b1, h1raw, 256, bnacc1);
  }
  k_bn_apply2<256, false><<<(NN * 128 + 255) / 256, 256, 0, stream>>>(
      h1raw, bnacc1, g1, bt1, (unsigned int*)h1);

  // ---- layer 2: z2 = h1 @ [Wl2;Wr2]^T; h2raw = agg(z2[:,:128]) + z2[:,128:] + b2 ----
  {
    dim3 g((NN + 127) / 128, 2);
    k_gemm_mfma<false, false><<<g, 256, 0, stream>>>(h1, 256, w2s, nullptr, z2, 256, nullptr);
  }
  k_aggb<128, 8, true, false, false><<<(NN + 3) / 4, 256, 0, stream>>>(
      (const unsigned int*)z2, 128, begend, col, (const unsigned int*)z2 + 64, 128, b2,
      h2raw, 128, nullptr, nullptr, nullptr);
  k_bn_stats2<128, false><<<512, 256, 0, stream>>>(h2raw, bnacc2);
  k_bn_apply2<128, true><<<(NN * 64 + 255) / 256, 256, 0, stream>>>(
      h2raw, bnacc2, g2, bt2, (unsigned int*)h2);

  // ---- layer 3: z3 = h2 @ [Wle;Wre]^T; emb = agg(z3[:,:64]) + z3[:,64:] + be; classifier ----
  {
    dim3 g((NN + 127) / 128, 1);
    k_gemm_mfma<false, false><<<g, 256, 0, stream>>>(h2, 128, w3s, nullptr, z3, 128, nullptr);
  }
  k_aggb<64, 8, true, false, true><<<(NN + 7) / 8, 256, 0, stream>>>(
      (const unsigned int*)z3, 64, begend, col, (const unsigned int*)z3 + 32, 64, be,
      emb, 64, Wc, bc, logits);
}